// Round 10
// baseline (125.332 us; speedup 1.0000x reference)
//
#include <hip/hip_runtime.h>

// MountainCar batched rollout: B=8192 envs, 500 sequential steps of a
// 2->64->1 MLP policy + dynamics.
//
// Round 10: KL=32 lanes/env -> 262144 threads = 4096 waves = 4 waves/SIMD.
// Rounds 4-9 showed a ~210k-cycle wall floor at 2 waves/SIMD caused by
// CORRELATED stalls (both waves run identical code in near-lockstep; their
// chain bubbles coincide, so cutting instructions didn't move the wall).
// 4 independent waves/SIMD fills those bubbles. Per-env issue rises only
// mildly: UPL 4->2, dynamics are SIMT-shared (a wave hosts 2 envs), and the
// reduction needs one extra stage: 4 DPP stages + ds_swizzle xor-16
// (offset 0x401F, static crossbar permute within each 32-lane half --
// exactly the env group; no LDS storage touched).
// Kept from R7: write-at-crossing (no per-step merges), intrinsic DPP
// (compiler owns the GFX9 DPP hazard), sign-free tanh, b2 seed on sub==0,
// deferred -0.1 reward scale, med3 clip.

constexpr int B = 8192;
constexpr int L = 64;
constexpr int MAX_STEPS = 500;
constexpr float GOAL_P = 0.5f;
constexpr float MIN_P  = -1.2f;
constexpr float MIN_V  = -0.07f;
constexpr float MAX_V  = 0.07f;

constexpr int KL  = 32;       // lanes per env
constexpr int UPL = L / KL;   // hidden units per lane = 2

template<int CTRL>
__device__ __forceinline__ float dpp_add(float x) {
  int y = __builtin_amdgcn_update_dpp(0, __float_as_int(x), CTRL, 0xf, 0xf, true);
  return x + __int_as_float(y);
}

// xor-16 lane swap within each 32-lane half (BitMode: xor=0x10, and=0x1F).
__device__ __forceinline__ float swz_add_x16(float x) {
  int y = __builtin_amdgcn_ds_swizzle(__float_as_int(x), 0x401F);
  return x + __int_as_float(y);
}

__global__ __launch_bounds__(256) void mc_kernel(
    const float* __restrict__ x,  const float* __restrict__ w1,
    const float* __restrict__ b1, const float* __restrict__ w2,
    const float* __restrict__ b2, float* __restrict__ out)
{
  int tid  = blockIdx.x * blockDim.x + threadIdx.x;
  int env  = tid >> 5;                 // env index
  int sub  = tid & 31;                 // lane-within-env
  int lane = threadIdx.x & 63;         // lane-within-wave

  constexpr float TS = 2.8853900817779268f;  // 2*log2(e), folded into w2/b2

  float w1a[UPL], w1b[UPL], b1r[UPL], w2r[UPL];
  const int j0 = sub * UPL;
#pragma unroll
  for (int i = 0; i < UPL; ++i) {
    w1a[i] = w1[j0 + i];          // w1[0][j]
    w1b[i] = w1[L + j0 + i];      // w1[1][j]
    b1r[i] = b1[j0 + i];
    w2r[i] = w2[j0 + i] * TS;     // w2[j][0], pre-scaled
  }
  const float b2seed = (sub == 0) ? b2[0] * TS : 0.0f;

  float4 st = reinterpret_cast<const float4*>(x)[env];
  const float r0 = st.w;
  float p = st.x, v = st.y, u = st.z;
  float racc = 0.0f;   // sum of u^2 over live steps

  unsigned long long live = __ballot(true);

  for (int stp = 0; stp < MAX_STEPS; ++stp) {
    float p1 = fmaxf(p, MIN_P);
    float v1 = (p <= MIN_P) ? 0.0f : v;

    // cos(3*p1): v_cos takes revolutions; independent of the MLP chain.
    float c = __builtin_amdgcn_cosf(p1 * 0.47746482927568601f);

    // Layer 1 (relu) + layer-2 partial dot (2 units/lane), b2 seed on sub 0.
    float h0 = fmaxf(fmaf(v1, w1b[0], fmaf(p1, w1a[0], b1r[0])), 0.0f);
    float h1 = fmaxf(fmaf(v1, w1b[1], fmaf(p1, w1a[1], b1r[1])), 0.0f);
    float s = fmaf(h1, w2r[1], fmaf(h0, w2r[0], b2seed));

    // 32-lane reduction: 4 DPP stages + crossbar xor-16.
    s = dpp_add<0xB1>(s);     // quad_perm [1,0,3,2] : + lane^1
    s = dpp_add<0x4E>(s);     // quad_perm [2,3,0,1] : + lane^2
    s = dpp_add<0x141>(s);    // row_half_mirror    : + lane^(4..7)
    s = dpp_add<0x140>(s);    // row_mirror         : + lane^(8..15)
    s = swz_add_x16(s);       // ds_swizzle xor-16  : + other 16-group

    // tanh, sign-free: 1 - 2/(exp2(s)+1); exact at both saturations.
    float e  = __builtin_amdgcn_exp2f(s);
    float u1 = fmaf(-2.0f, __builtin_amdgcn_rcpf(e + 1.0f), 1.0f);

    float v2 = fmaf(-0.0025f, c, fmaf(0.0015f, u1, v1));
    v2 = __builtin_amdgcn_fmed3f(v2, MIN_V, MAX_V);

    // Unconditional state update (write-at-crossing).
    p = p1 + v2;
    v = v2;
    u = u1;
    racc = fmaf(u1, u1, racc);

    // Newly-crossed envs commit their final row immediately.
    unsigned long long crossed = __ballot(p > GOAL_P) & live;
    if (crossed) {                        // wave-uniform, rarely taken
      live &= ~crossed;
      if (((crossed >> lane) & 1ull) && sub == 0) {
        float rout = fmaf(-0.1f, racc, r0) + 100.0f;
        reinterpret_cast<float4*>(out)[env] = make_float4(p, v, u, rout);
      }
      if (!live) return;                  // both envs in wave committed
    }
  }

  // Envs that never crossed within MAX_STEPS: no +100.
  if (((live >> lane) & 1ull) && sub == 0) {
    float rout = fmaf(-0.1f, racc, r0);
    reinterpret_cast<float4*>(out)[env] = make_float4(p, v, u, rout);
  }
}

extern "C" void kernel_launch(void* const* d_in, const int* in_sizes, int n_in,
                              void* d_out, int out_size, void* d_ws, size_t ws_size,
                              hipStream_t stream) {
  const float* x  = (const float*)d_in[0];
  const float* w1 = (const float*)d_in[1];
  const float* b1 = (const float*)d_in[2];
  const float* w2 = (const float*)d_in[3];
  const float* b2 = (const float*)d_in[4];
  float* out = (float*)d_out;

  constexpr int threads = B * KL;  // 262144 -> 4096 waves -> 4 waves/SIMD
  mc_kernel<<<threads / 256, 256, 0, stream>>>(x, w1, b1, w2, b2, out);
}

// Round 11
// 101.806 us; speedup vs baseline: 1.2311x; 1.2311x over previous
//
#include <hip/hip_runtime.h>

// MountainCar batched rollout: B=8192 envs, 500 sequential steps of a
// 2->64->1 MLP policy + dynamics.
//
// Round 11: KL=8 lanes/env + 512-THREAD BLOCKS (half-chip concentration).
// Cross-round model: wall/step = issue/SIMD + stall(W); stall collapses
// ~430->~100 cyc once W>=2 waves/SIMD, after which wall tracks issue.
// KL=8 minimizes chip-wide issue (1024 waves x ~116 cyc/step vs KL=16's
// 2048 x 157) but standard 256-blocks spread it 1 wave/SIMD (R1: 548
// cyc/step). 512-thread blocks force each block's 8 waves onto one CU =
// 2 waves/SIMD on 128 CUs; idle CUs are free (zero memory pressure).
// Per-active-SIMD issue ~232 cyc/step, 26% below R7's 314.
// Kept: write-at-crossing, intrinsic DPP 3-stage butterfly (R1-proven),
// sign-free tanh, b2 seed on sub==0, deferred -0.1 reward, med3 clip.
// New: dual-chain layer-2 accumulation (depth 9 -> 6 for UPL=8, +1 instr).

constexpr int B = 8192;
constexpr int L = 64;
constexpr int MAX_STEPS = 500;
constexpr float GOAL_P = 0.5f;
constexpr float MIN_P  = -1.2f;
constexpr float MIN_V  = -0.07f;
constexpr float MAX_V  = 0.07f;

constexpr int KL  = 8;        // lanes per env
constexpr int UPL = L / KL;   // hidden units per lane = 8

template<int CTRL>
__device__ __forceinline__ float dpp_add(float x) {
  int y = __builtin_amdgcn_update_dpp(0, __float_as_int(x), CTRL, 0xf, 0xf, true);
  return x + __int_as_float(y);
}

__global__ __launch_bounds__(512) void mc_kernel(
    const float* __restrict__ x,  const float* __restrict__ w1,
    const float* __restrict__ b1, const float* __restrict__ w2,
    const float* __restrict__ b2, float* __restrict__ out)
{
  int tid  = blockIdx.x * blockDim.x + threadIdx.x;
  int env  = tid >> 3;                 // env index
  int sub  = tid & 7;                  // lane-within-env
  int lane = threadIdx.x & 63;         // lane-within-wave

  constexpr float TS = 2.8853900817779268f;  // 2*log2(e), folded into w2/b2

  float w1a[UPL], w1b[UPL], b1r[UPL], w2r[UPL];
  const int j0 = sub * UPL;
#pragma unroll
  for (int i = 0; i < UPL; ++i) {
    w1a[i] = w1[j0 + i];          // w1[0][j]
    w1b[i] = w1[L + j0 + i];      // w1[1][j]
    b1r[i] = b1[j0 + i];
    w2r[i] = w2[j0 + i] * TS;     // w2[j][0], pre-scaled
  }
  const float b2seed = (sub == 0) ? b2[0] * TS : 0.0f;

  float4 st = reinterpret_cast<const float4*>(x)[env];
  const float r0 = st.w;
  float p = st.x, v = st.y, u = st.z;
  float racc = 0.0f;   // sum of u^2 over live steps

  unsigned long long live = __ballot(true);

  for (int stp = 0; stp < MAX_STEPS; ++stp) {
    float p1 = fmaxf(p, MIN_P);
    float v1 = (p <= MIN_P) ? 0.0f : v;

    // cos(3*p1): v_cos takes revolutions; independent of the MLP chain.
    float c = __builtin_amdgcn_cosf(p1 * 0.47746482927568601f);

    // Layer 1 (relu): 8 independent units per lane.
    float h[UPL];
#pragma unroll
    for (int i = 0; i < UPL; ++i)
      h[i] = fmaxf(fmaf(v1, w1b[i], fmaf(p1, w1a[i], b1r[i])), 0.0f);

    // Layer 2: dual accumulation chains (depth 6 vs serial 9).
    float se = fmaf(h[6], w2r[6], fmaf(h[4], w2r[4],
               fmaf(h[2], w2r[2], fmaf(h[0], w2r[0], b2seed))));
    float so = fmaf(h[7], w2r[7], fmaf(h[5], w2r[5],
               fmaf(h[3], w2r[3], h[1] * w2r[1])));
    float s = se + so;

    // 8-lane butterfly (R1-proven stages); all 8 lanes get the full logit.
    s = dpp_add<0xB1>(s);     // quad_perm [1,0,3,2] : + lane^1
    s = dpp_add<0x4E>(s);     // quad_perm [2,3,0,1] : + lane^2
    s = dpp_add<0x141>(s);    // row_half_mirror    : + other quad

    // tanh, sign-free: 1 - 2/(exp2(s)+1); exact at both saturations.
    float e  = __builtin_amdgcn_exp2f(s);
    float u1 = fmaf(-2.0f, __builtin_amdgcn_rcpf(e + 1.0f), 1.0f);

    float v2 = fmaf(-0.0025f, c, fmaf(0.0015f, u1, v1));
    v2 = __builtin_amdgcn_fmed3f(v2, MIN_V, MAX_V);

    // Unconditional state update (write-at-crossing).
    p = p1 + v2;
    v = v2;
    u = u1;
    racc = fmaf(u1, u1, racc);

    // Newly-crossed envs commit their final row immediately.
    unsigned long long crossed = __ballot(p > GOAL_P) & live;
    if (crossed) {                        // wave-uniform, rarely taken
      live &= ~crossed;
      if (((crossed >> lane) & 1ull) && sub == 0) {
        float rout = fmaf(-0.1f, racc, r0) + 100.0f;
        reinterpret_cast<float4*>(out)[env] = make_float4(p, v, u, rout);
      }
      if (!live) return;                  // all 8 envs in wave committed
    }
  }

  // Envs that never crossed within MAX_STEPS: no +100.
  if (((live >> lane) & 1ull) && sub == 0) {
    float rout = fmaf(-0.1f, racc, r0);
    reinterpret_cast<float4*>(out)[env] = make_float4(p, v, u, rout);
  }
}

extern "C" void kernel_launch(void* const* d_in, const int* in_sizes, int n_in,
                              void* d_out, int out_size, void* d_ws, size_t ws_size,
                              hipStream_t stream) {
  const float* x  = (const float*)d_in[0];
  const float* w1 = (const float*)d_in[1];
  const float* b1 = (const float*)d_in[2];
  const float* w2 = (const float*)d_in[3];
  const float* b2 = (const float*)d_in[4];
  float* out = (float*)d_out;

  constexpr int threads = B * KL;      // 65536
  // 512-thread blocks: 128 blocks; each block's 8 waves sit 2-per-SIMD on
  // one CU -> 2 waves/SIMD on 128 CUs (low-stall regime at minimum issue).
  mc_kernel<<<threads / 512, 512, 0, stream>>>(x, w1, b1, w2, b2, out);
}

// Round 12
// 85.265 us; speedup vs baseline: 1.4699x; 1.1940x over previous
//
#include <hip/hip_runtime.h>

// MountainCar batched rollout: B=8192 envs, 500 sequential steps of a
// 2->64->1 MLP policy + dynamics.
//
// Round 12 = R7 (proven best, 83.6us) + ANTI-PHASE WAVE STAGGER.
// Cross-round model: wall/step = issue/SIMD + stall; stall ~90 cyc only
// when the 2 co-resident waves/SIMD are phase-offset (R7: different
// blocks), ~290-430 when lockstepped (R11: same block) or solo (R1/R9).
// R8 proved issue cuts don't move the wall at 2 waves/SIMD -> the lever is
// decorrelation. Here: odd waves s_sleep ~192 cyc once before the loop
// (~half of R7's 402-cyc step), so one wave's issue-dense MLP phase
// overlaps the other's stall-dense butterfly->tanh phase each step.
// Everything else byte-identical to R7: KL=16, write-at-crossing,
// intrinsic DPP butterfly, sign-free tanh, b2 seed, deferred reward, med3.

constexpr int B = 8192;
constexpr int L = 64;
constexpr int MAX_STEPS = 500;
constexpr float GOAL_P = 0.5f;
constexpr float MIN_P  = -1.2f;
constexpr float MIN_V  = -0.07f;
constexpr float MAX_V  = 0.07f;

constexpr int KL  = 16;       // lanes per env
constexpr int UPL = L / KL;   // hidden units per lane = 4

template<int CTRL>
__device__ __forceinline__ float dpp_add(float x) {
  int y = __builtin_amdgcn_update_dpp(0, __float_as_int(x), CTRL, 0xf, 0xf, true);
  return x + __int_as_float(y);
}

__global__ __launch_bounds__(256) void mc_kernel(
    const float* __restrict__ x,  const float* __restrict__ w1,
    const float* __restrict__ b1, const float* __restrict__ w2,
    const float* __restrict__ b2, float* __restrict__ out)
{
  int tid  = blockIdx.x * blockDim.x + threadIdx.x;
  int env  = tid >> 4;                 // env index
  int sub  = tid & 15;                 // lane-within-env
  int lane = threadIdx.x & 63;         // lane-within-wave

  constexpr float TS = 2.8853900817779268f;  // 2*log2(e), folded into w2/b2

  float w1a[UPL], w1b[UPL], b1r[UPL], w2r[UPL];
  const int j0 = sub * UPL;
#pragma unroll
  for (int i = 0; i < UPL; ++i) {
    w1a[i] = w1[j0 + i];          // w1[0][j]
    w1b[i] = w1[L + j0 + i];      // w1[1][j]
    b1r[i] = b1[j0 + i];
    w2r[i] = w2[j0 + i] * TS;     // w2[j][0], pre-scaled
  }
  const float b2seed = (sub == 0) ? b2[0] * TS : 0.0f;

  float4 st = reinterpret_cast<const float4*>(x)[env];
  const float r0 = st.w;
  float p = st.x, v = st.y, u = st.z;
  float racc = 0.0f;   // sum of u^2 over live steps

  unsigned long long live = __ballot(true);

  // ANTI-PHASE STAGGER: odd waves yield ~192 cycles once, so the two
  // co-resident waves per SIMD run half-a-step out of phase and fill each
  // other's dependency-stall bubbles (issue slots are NOT consumed).
  if ((threadIdx.x >> 6) & 1) {
    __builtin_amdgcn_s_sleep(3);
  }

  for (int stp = 0; stp < MAX_STEPS; ++stp) {
    float p1 = fmaxf(p, MIN_P);
    float v1 = (p <= MIN_P) ? 0.0f : v;

    // cos(3*p1): v_cos takes revolutions; independent of the MLP chain.
    float c = __builtin_amdgcn_cosf(p1 * 0.47746482927568601f);

    // Layer 1 (relu) + layer-2 partial dot, seeded with b2 on lane 0.
    float h0 = fmaxf(fmaf(v1, w1b[0], fmaf(p1, w1a[0], b1r[0])), 0.0f);
    float h1 = fmaxf(fmaf(v1, w1b[1], fmaf(p1, w1a[1], b1r[1])), 0.0f);
    float h2 = fmaxf(fmaf(v1, w1b[2], fmaf(p1, w1a[2], b1r[2])), 0.0f);
    float h3 = fmaxf(fmaf(v1, w1b[3], fmaf(p1, w1a[3], b1r[3])), 0.0f);
    float s = b2seed;
    s = fmaf(h0, w2r[0], s);
    s = fmaf(h1, w2r[1], s);
    s = fmaf(h2, w2r[2], s);
    s = fmaf(h3, w2r[3], s);

    // 16-lane butterfly; every lane ends with the full pre-scaled logit.
    s = dpp_add<0xB1>(s);     // quad_perm [1,0,3,2] : + lane^1
    s = dpp_add<0x4E>(s);     // quad_perm [2,3,0,1] : + lane^2
    s = dpp_add<0x141>(s);    // row_half_mirror    : + lane^(4..7)
    s = dpp_add<0x140>(s);    // row_mirror         : + lane^(8..15)

    // tanh, sign-free: 1 - 2/(exp2(s)+1); exact at both saturations.
    float e  = __builtin_amdgcn_exp2f(s);
    float u1 = fmaf(-2.0f, __builtin_amdgcn_rcpf(e + 1.0f), 1.0f);

    float v2 = fmaf(-0.0025f, c, fmaf(0.0015f, u1, v1));
    v2 = __builtin_amdgcn_fmed3f(v2, MIN_V, MAX_V);

    // Unconditional state update (write-at-crossing).
    p = p1 + v2;
    v = v2;
    u = u1;
    racc = fmaf(u1, u1, racc);

    // Newly-crossed envs commit their final row immediately.
    unsigned long long crossed = __ballot(p > GOAL_P) & live;
    if (crossed) {                        // wave-uniform, rarely taken
      live &= ~crossed;
      if (((crossed >> lane) & 1ull) && sub == 0) {
        float rout = fmaf(-0.1f, racc, r0) + 100.0f;
        reinterpret_cast<float4*>(out)[env] = make_float4(p, v, u, rout);
      }
      if (!live) return;                  // all 4 envs in wave committed
    }
  }

  // Envs that never crossed within MAX_STEPS: no +100.
  if (((live >> lane) & 1ull) && sub == 0) {
    float rout = fmaf(-0.1f, racc, r0);
    reinterpret_cast<float4*>(out)[env] = make_float4(p, v, u, rout);
  }
}

extern "C" void kernel_launch(void* const* d_in, const int* in_sizes, int n_in,
                              void* d_out, int out_size, void* d_ws, size_t ws_size,
                              hipStream_t stream) {
  const float* x  = (const float*)d_in[0];
  const float* w1 = (const float*)d_in[1];
  const float* b1 = (const float*)d_in[2];
  const float* w2 = (const float*)d_in[3];
  const float* b2 = (const float*)d_in[4];
  float* out = (float*)d_out;

  constexpr int threads = B * KL;  // 131072 -> 2048 waves -> 2 waves/SIMD
  mc_kernel<<<threads / 256, 256, 0, stream>>>(x, w1, b1, w2, b2, out);
}